// Round 1
// baseline (3290.570 us; speedup 1.0000x reference)
//
#include <hip/hip_runtime.h>
#include <hip/hip_bf16.h>
#include <cstdint>
#include <cstddef>

// GCNEncoder: two-branch GCN on MI355X.
// Pipeline per call (all deterministic, all on `stream`):
//   1) memset zero-region (deg/cursor/S/cnt)
//   2) degree histogram per edge set (atomicAdd int)
//   3) dinv = 1/sqrt(deg+1)   (+1 = self loop)
//   4) exclusive scan of per-node edge counts -> CSR row_ptr (3-kernel scan)
//   5) counting-sort edges into CSR (src, norm = dinv[src]*dinv[dst])
//   6) GEMM1: h[50000x512] = x @ [W_l1 | W_g1]   (fp32 this round; bf16 MFMA next)
//   7) conv1 aggregation (CSR pull, wave-per-node) + bias + relu -> xl[50000x512]
//   8) conv2 fused with mean-pool: S[g] = sum_e norm_e * xl[src_e]  (linearity:
//      pool(conv2) = (S[g] @ W2)/cnt_g + b2), per-node bracket + atomicAdd to 64x256
//   9) final: per-graph (S@W2)/cnt + b2, concat, @W_fuse + b_fuse, relu -> out[64x128]

#define N_NODES 50000
#define N_GRAPHS 64
#define IN_DIM 2063
#define HIDDEN 256
#define OUT_DIM 128
#define EDGES_L 800000
#define EDGES_G 1600000
#define HCOLS 512  // [local 0..255 | global 256..511]

// ---------------------------------------------------------------- small kernels
__global__ void k_degree(const int* __restrict__ dst, int E, int* __restrict__ deg) {
  int e = blockIdx.x * blockDim.x + threadIdx.x;
  if (e < E) atomicAdd(&deg[dst[e]], 1);
}

__global__ void k_dinv(const int* __restrict__ degL, const int* __restrict__ degG,
                       float* __restrict__ dinvL, float* __restrict__ dinvG) {
  int i = blockIdx.x * blockDim.x + threadIdx.x;
  if (i < N_NODES) {
    dinvL[i] = 1.0f / sqrtf((float)(degL[i] + 1));
    dinvG[i] = 1.0f / sqrtf((float)(degG[i] + 1));
  }
}

// scan step A: per-1024-block inclusive scan (Hillis-Steele)
__global__ void k_scan_block(const int* __restrict__ cnts, int n,
                             int* __restrict__ incl, int* __restrict__ bsums) {
  __shared__ int s[1024];
  int t = threadIdx.x;
  int i = blockIdx.x * 1024 + t;
  int v = (i < n) ? cnts[i] : 0;
  s[t] = v;
  __syncthreads();
  for (int off = 1; off < 1024; off <<= 1) {
    int x = (t >= off) ? s[t - off] : 0;
    __syncthreads();
    s[t] += x;
    __syncthreads();
  }
  if (i < n) incl[i] = s[t];
  if (t == 1023) bsums[blockIdx.x] = s[1023];
}

// scan step B: exclusive scan of the 49 block sums
__global__ void k_scan_tops(int* __restrict__ bsums, int nb) {
  __shared__ int s[64];
  int t = threadIdx.x;
  if (t < nb) s[t] = bsums[t];
  __syncthreads();
  if (t == 0) {
    int run = 0;
    for (int b = 0; b < nb; b++) { int v = s[b]; s[b] = run; run += v; }
  }
  __syncthreads();
  if (t < nb) bsums[t] = s[t];
}

// scan step C: row_ptr[i+1] = incl[i] + boffs[block]; row_ptr[0] = 0
__global__ void k_scan_fix(const int* __restrict__ incl, const int* __restrict__ boffs,
                           int n, int* __restrict__ row_ptr) {
  int i = blockIdx.x * blockDim.x + threadIdx.x;
  if (i < n) row_ptr[i + 1] = incl[i] + boffs[i >> 10];
  if (i == 0) row_ptr[0] = 0;
}

// counting-sort edges into CSR slots; store src and norm
__global__ void k_scatter(const int* __restrict__ src, const int* __restrict__ dst, int E,
                          const float* __restrict__ dinv, const int* __restrict__ row_ptr,
                          int* __restrict__ cursor, int* __restrict__ s_src,
                          float* __restrict__ s_nrm) {
  int e = blockIdx.x * blockDim.x + threadIdx.x;
  if (e < E) {
    int d = dst[e], s = src[e];
    int pos = row_ptr[d] + atomicAdd(&cursor[d], 1);
    s_src[pos] = s;
    s_nrm[pos] = dinv[s] * dinv[d];
  }
}

__global__ void k_count(const int* __restrict__ batch, int* __restrict__ cnt) {
  int i = blockIdx.x * blockDim.x + threadIdx.x;
  if (i < N_NODES) atomicAdd(&cnt[batch[i]], 1);
}

// ---------------------------------------------------------------- GEMM1 (fp32)
// h[50000 x 512] = x @ [W_l1 | W_g1].  Classic 128x128x8 SGEMM, 256 threads, 8x8/thread.
#define BM 128
#define BN 128
#define BK 8

__launch_bounds__(256, 2)
__global__ void k_sgemm(const float* __restrict__ A, const float* __restrict__ Wl,
                        const float* __restrict__ Wg, float* __restrict__ H) {
  __shared__ float As[BK][BM];
  __shared__ float Bs[BK][BN];
  const int tid = threadIdx.x;
  const int bn = blockIdx.x;  // 0..3 -> H cols [bn*128, bn*128+128)
  const int bm = blockIdx.y;
  const float* __restrict__ B = (bn < 2) ? Wl : Wg;
  const int bcol = (bn & 1) * BN;  // column offset inside the 256-wide W
  const int row_base = bm * BM;
  const int r0 = (tid >> 4) << 3;
  const int c0 = (tid & 15) << 3;
  const int la_row = tid >> 1;
  const int la_k = (tid & 1) * 4;
  const int lb_k = tid >> 5;
  const int lb_n = (tid & 31) * 4;

  float acc[8][8];
#pragma unroll
  for (int i = 0; i < 8; i++)
#pragma unroll
    for (int j = 0; j < 8; j++) acc[i][j] = 0.f;

  const int arow = row_base + la_row;
  const bool arow_ok = (arow < N_NODES);
  const float* __restrict__ Arow = A + (size_t)arow * IN_DIM;

  for (int k0 = 0; k0 < IN_DIM; k0 += BK) {
    // A tile (scalar loads: row stride 2063 is odd -> no guaranteed 16B alignment)
    float a0 = 0.f, a1 = 0.f, a2 = 0.f, a3 = 0.f;
    int kk = k0 + la_k;
    if (arow_ok) {
      if (kk + 3 < IN_DIM) {
        a0 = Arow[kk]; a1 = Arow[kk + 1]; a2 = Arow[kk + 2]; a3 = Arow[kk + 3];
      } else {
        if (kk < IN_DIM) a0 = Arow[kk];
        if (kk + 1 < IN_DIM) a1 = Arow[kk + 1];
        if (kk + 2 < IN_DIM) a2 = Arow[kk + 2];
      }
    }
    As[la_k + 0][la_row] = a0;
    As[la_k + 1][la_row] = a1;
    As[la_k + 2][la_row] = a2;
    As[la_k + 3][la_row] = a3;
    // B tile (16B-aligned: stride 256)
    float4 bv = make_float4(0.f, 0.f, 0.f, 0.f);
    int kb = k0 + lb_k;
    if (kb < IN_DIM) bv = *(const float4*)(B + (size_t)kb * HIDDEN + bcol + lb_n);
    *(float4*)&Bs[lb_k][lb_n] = bv;
    __syncthreads();
#pragma unroll
    for (int k = 0; k < BK; k++) {
      float a[8], b[8];
      *(float4*)&a[0] = *(const float4*)&As[k][r0];
      *(float4*)&a[4] = *(const float4*)&As[k][r0 + 4];
      *(float4*)&b[0] = *(const float4*)&Bs[k][c0];
      *(float4*)&b[4] = *(const float4*)&Bs[k][c0 + 4];
#pragma unroll
      for (int i = 0; i < 8; i++)
#pragma unroll
        for (int j = 0; j < 8; j++) acc[i][j] = fmaf(a[i], b[j], acc[i][j]);
    }
    __syncthreads();
  }
  const int colb = bn * BN + c0;
#pragma unroll
  for (int i = 0; i < 8; i++) {
    int row = row_base + r0 + i;
    if (row < N_NODES) {
      float* p = H + (size_t)row * HCOLS + colb;
      *(float4*)p = make_float4(acc[i][0], acc[i][1], acc[i][2], acc[i][3]);
      *(float4*)(p + 4) = make_float4(acc[i][4], acc[i][5], acc[i][6], acc[i][7]);
    }
  }
}

// ------------------------------------------------------- conv1 aggregation (pull)
// one wave (64 lanes x float4 = 256 floats) per dst node
__global__ void k_agg1(const float* __restrict__ h, int hoff, const float* __restrict__ dinv,
                       const int* __restrict__ row_ptr, const int* __restrict__ srcs,
                       const float* __restrict__ norms, const float* __restrict__ bias,
                       float* __restrict__ xl, int xoff) {
  int gt = blockIdx.x * blockDim.x + threadIdx.x;
  int node = gt >> 6;
  int lane = gt & 63;
  if (node >= N_NODES) return;
  float di = dinv[node];
  float w0 = di * di;  // self-loop norm
  float4 a = *(const float4*)(h + (size_t)node * HCOLS + hoff + lane * 4);
  a.x *= w0; a.y *= w0; a.z *= w0; a.w *= w0;
  int e0 = row_ptr[node], e1 = row_ptr[node + 1];
  for (int e = e0; e < e1; e++) {
    int s = srcs[e];
    float w = norms[e];
    float4 v = *(const float4*)(h + (size_t)s * HCOLS + hoff + lane * 4);
    a.x = fmaf(w, v.x, a.x);
    a.y = fmaf(w, v.y, a.y);
    a.z = fmaf(w, v.z, a.z);
    a.w = fmaf(w, v.w, a.w);
  }
  float4 b = *(const float4*)(bias + lane * 4);
  a.x = fmaxf(a.x + b.x, 0.f);
  a.y = fmaxf(a.y + b.y, 0.f);
  a.z = fmaxf(a.z + b.z, 0.f);
  a.w = fmaxf(a.w + b.w, 0.f);
  *(float4*)(xl + (size_t)node * HCOLS + xoff + lane * 4) = a;
}

// ---------------------------------------- conv2 fused into pooling: per-graph S
__global__ void k_conv2(const float* __restrict__ xl, int off, const float* __restrict__ dinv,
                        const int* __restrict__ row_ptr, const int* __restrict__ srcs,
                        const float* __restrict__ norms, const int* __restrict__ batch,
                        float* __restrict__ S) {
  int gt = blockIdx.x * blockDim.x + threadIdx.x;
  int node = gt >> 6;
  int lane = gt & 63;
  if (node >= N_NODES) return;
  float di = dinv[node];
  float w0 = di * di;
  float4 a = *(const float4*)(xl + (size_t)node * HCOLS + off + lane * 4);
  a.x *= w0; a.y *= w0; a.z *= w0; a.w *= w0;
  int e0 = row_ptr[node], e1 = row_ptr[node + 1];
  for (int e = e0; e < e1; e++) {
    int s = srcs[e];
    float w = norms[e];
    float4 v = *(const float4*)(xl + (size_t)s * HCOLS + off + lane * 4);
    a.x = fmaf(w, v.x, a.x);
    a.y = fmaf(w, v.y, a.y);
    a.z = fmaf(w, v.z, a.z);
    a.w = fmaf(w, v.w, a.w);
  }
  float* sp = S + (size_t)batch[node] * HIDDEN + lane * 4;
  atomicAdd(sp + 0, a.x);
  atomicAdd(sp + 1, a.y);
  atomicAdd(sp + 2, a.z);
  atomicAdd(sp + 3, a.w);
}

// ---------------------------------------------------------------- final fuse
__global__ void k_final(const float* __restrict__ S,  // [2][64][256]
                        const float* __restrict__ Wl2, const float* __restrict__ bl2,
                        const float* __restrict__ Wg2, const float* __restrict__ bg2,
                        const float* __restrict__ Wf, const float* __restrict__ bf,
                        const int* __restrict__ cnt, float* __restrict__ out) {
  __shared__ float pl[OUT_DIM], pg[OUT_DIM];
  int g = blockIdx.x, t = threadIdx.x;
  float invc = 1.0f / fmaxf((float)cnt[g], 1.0f);
  const float* Sl = S + (size_t)g * HIDDEN;
  const float* Sg = S + (size_t)N_GRAPHS * HIDDEN + (size_t)g * HIDDEN;
  float al = 0.f, ag = 0.f;
  for (int k = 0; k < HIDDEN; k++) {
    al = fmaf(Sl[k], Wl2[k * OUT_DIM + t], al);
    ag = fmaf(Sg[k], Wg2[k * OUT_DIM + t], ag);
  }
  pl[t] = al * invc + bl2[t];
  pg[t] = ag * invc + bg2[t];
  __syncthreads();
  float o = bf[t];
  for (int j = 0; j < OUT_DIM; j++) {
    o = fmaf(pl[j], Wf[j * OUT_DIM + t], o);
    o = fmaf(pg[j], Wf[(OUT_DIM + j) * OUT_DIM + t], o);
  }
  out[(size_t)g * OUT_DIM + t] = fmaxf(o, 0.f);
}

// ---------------------------------------------------------------- launch
extern "C" void kernel_launch(void* const* d_in, const int* in_sizes, int n_in,
                              void* d_out, int out_size, void* d_ws, size_t ws_size,
                              hipStream_t stream) {
  const float* x = (const float*)d_in[0];
  const int* el = (const int*)d_in[1];
  const int* eg = (const int*)d_in[2];
  const int* batch = (const int*)d_in[3];
  const float* Wl1 = (const float*)d_in[4];
  const float* bl1 = (const float*)d_in[5];
  const float* Wl2 = (const float*)d_in[6];
  const float* bl2 = (const float*)d_in[7];
  const float* Wg1 = (const float*)d_in[8];
  const float* bg1 = (const float*)d_in[9];
  const float* Wg2 = (const float*)d_in[10];
  const float* bg2 = (const float*)d_in[11];
  const float* Wf = (const float*)d_in[12];
  const float* bf = (const float*)d_in[13];
  float* out = (float*)d_out;
  char* ws = (char*)d_ws;

  // ---- workspace layout (256B aligned). Zero-region first (single memset).
  const size_t NPAD = 200192;  // 50000*4 padded
  size_t off = 0;
  int* deg_l = (int*)(ws + off); off += NPAD;
  int* deg_g = (int*)(ws + off); off += NPAD;
  int* cur_l = (int*)(ws + off); off += NPAD;
  int* cur_g = (int*)(ws + off); off += NPAD;
  float* S = (float*)(ws + off); off += (size_t)2 * N_GRAPHS * HIDDEN * 4;  // 128KB
  int* cnt = (int*)(ws + off); off += 256;
  const size_t zero_bytes = off;
  float* dinv_l = (float*)(ws + off); off += NPAD;
  float* dinv_g = (float*)(ws + off); off += NPAD;
  int* row_l = (int*)(ws + off); off += NPAD;  // 50001 ints fits in 200192
  int* row_g = (int*)(ws + off); off += NPAD;
  int* incl = (int*)(ws + off); off += NPAD;
  int* bsums = (int*)(ws + off); off += 256;
  int* srcs_l = (int*)(ws + off); off += (size_t)EDGES_L * 4;
  float* norm_l = (float*)(ws + off); off += (size_t)EDGES_L * 4;
  int* srcs_g = (int*)(ws + off); off += (size_t)EDGES_G * 4;
  float* norm_g = (float*)(ws + off); off += (size_t)EDGES_G * 4;
  float* h = (float*)(ws + off); off += (size_t)N_NODES * HCOLS * 4;   // 102.4 MB
  float* xl = (float*)(ws + off); off += (size_t)N_NODES * HCOLS * 4;  // 102.4 MB
  // total ~226 MB

  const int* srcL = el;
  const int* dstL = el + EDGES_L;
  const int* srcG = eg;
  const int* dstG = eg + EDGES_G;
  float* S_l = S;
  float* S_g = S + (size_t)N_GRAPHS * HIDDEN;

  hipMemsetAsync(ws, 0, zero_bytes, stream);

  k_degree<<<(EDGES_L + 255) / 256, 256, 0, stream>>>(dstL, EDGES_L, deg_l);
  k_degree<<<(EDGES_G + 255) / 256, 256, 0, stream>>>(dstG, EDGES_G, deg_g);
  k_dinv<<<(N_NODES + 255) / 256, 256, 0, stream>>>(deg_l, deg_g, dinv_l, dinv_g);

  const int NB = (N_NODES + 1023) / 1024;  // 49
  k_scan_block<<<NB, 1024, 0, stream>>>(deg_l, N_NODES, incl, bsums);
  k_scan_tops<<<1, 64, 0, stream>>>(bsums, NB);
  k_scan_fix<<<(N_NODES + 255) / 256, 256, 0, stream>>>(incl, bsums, N_NODES, row_l);
  k_scan_block<<<NB, 1024, 0, stream>>>(deg_g, N_NODES, incl, bsums);
  k_scan_tops<<<1, 64, 0, stream>>>(bsums, NB);
  k_scan_fix<<<(N_NODES + 255) / 256, 256, 0, stream>>>(incl, bsums, N_NODES, row_g);

  k_scatter<<<(EDGES_L + 255) / 256, 256, 0, stream>>>(srcL, dstL, EDGES_L, dinv_l, row_l,
                                                       cur_l, srcs_l, norm_l);
  k_scatter<<<(EDGES_G + 255) / 256, 256, 0, stream>>>(srcG, dstG, EDGES_G, dinv_g, row_g,
                                                       cur_g, srcs_g, norm_g);
  k_count<<<(N_NODES + 255) / 256, 256, 0, stream>>>(batch, cnt);

  dim3 ggrid(4, (N_NODES + BM - 1) / BM);  // 4 x 391
  k_sgemm<<<ggrid, 256, 0, stream>>>(x, Wl1, Wg1, h);

  const int aggGrid = (N_NODES * 64 + 255) / 256;  // 12500 blocks, wave-per-node
  k_agg1<<<aggGrid, 256, 0, stream>>>(h, 0, dinv_l, row_l, srcs_l, norm_l, bl1, xl, 0);
  k_agg1<<<aggGrid, 256, 0, stream>>>(h, 256, dinv_g, row_g, srcs_g, norm_g, bg1, xl, 256);

  k_conv2<<<aggGrid, 256, 0, stream>>>(xl, 0, dinv_l, row_l, srcs_l, norm_l, batch, S_l);
  k_conv2<<<aggGrid, 256, 0, stream>>>(xl, 256, dinv_g, row_g, srcs_g, norm_g, batch, S_g);

  k_final<<<N_GRAPHS, OUT_DIM, 0, stream>>>(S, Wl2, bl2, Wg2, bg2, Wf, bf, cnt, out);
}

// Round 2
// 2047.062 us; speedup vs baseline: 1.6075x; 1.6075x over previous
//
#include <hip/hip_runtime.h>
#include <hip/hip_bf16.h>
#include <cstdint>
#include <cstddef>

// GCNEncoder: two-branch GCN on MI355X.
// Round 2: GEMM1 moved to bf16 MFMA (16x16x32), h/xl stored bf16 (half gather bytes).
// Pipeline:
//   1) memset zero-region (deg/cursor/S/cnt)
//   2) cvt x -> bf16 xb[50048][2112] (zero-padded), W -> bf16 transposed Wt[512][2112]
//   3) degree / dinv / scan -> CSR / scatter (counting sort) / graph counts
//   4) GEMM1 (MFMA): h[50000x512]bf16 = xb @ Wt^T
//   5) conv1 agg (CSR pull, wave/node, bf16 gather, fp32 acc) + bias + relu -> xl bf16
//   6) conv2 fused w/ mean-pool numerator: S[g][256] += norm-weighted xl rows (atomics)
//   7) final: (S@W2)/cnt + b2, concat, @W_fuse + b_fuse, relu -> out[64x128] fp32

#define N_NODES 50000
#define N_GRAPHS 64
#define IN_DIM 2063
#define HIDDEN 256
#define OUT_DIM 128
#define EDGES_L 800000
#define EDGES_G 1600000
#define HCOLS 512   // [local 0..255 | global 256..511]
#define KPAD 2112   // 33 * 64
#define MPAD 50048  // 391 * 128

typedef __attribute__((ext_vector_type(8))) __bf16 bf16x8;
typedef __attribute__((ext_vector_type(4))) float f32x4;

__device__ __forceinline__ float bf2f(unsigned short u) {
  union { unsigned int i; float f; } c; c.i = ((unsigned int)u) << 16; return c.f;
}
__device__ __forceinline__ unsigned short f2bf(float f) {
  __hip_bfloat16 h = __float2bfloat16(f);
  return *reinterpret_cast<unsigned short*>(&h);
}

// ---------------------------------------------------------------- converts
__global__ void k_cvt_x(const float* __restrict__ x, unsigned short* __restrict__ xb) {
  const int G = KPAD / 4;  // 528 groups of 4 per row
  long long i = (long long)blockIdx.x * blockDim.x + threadIdx.x;
  if (i >= (long long)MPAD * G) return;
  int row = (int)(i / G);
  int k = (int)(i - (long long)row * G) * 4;
  ushort4 o;
  float v0 = 0.f, v1 = 0.f, v2 = 0.f, v3 = 0.f;
  if (row < N_NODES) {
    const float* xr = x + (size_t)row * IN_DIM;
    if (k + 0 < IN_DIM) v0 = xr[k + 0];
    if (k + 1 < IN_DIM) v1 = xr[k + 1];
    if (k + 2 < IN_DIM) v2 = xr[k + 2];
    if (k + 3 < IN_DIM) v3 = xr[k + 3];
  }
  o.x = f2bf(v0); o.y = f2bf(v1); o.z = f2bf(v2); o.w = f2bf(v3);
  *(ushort4*)(xb + (size_t)row * KPAD + k) = o;
}

// Wt[n][k]: n in [0,256) from W_l1, [256,512) from W_g1; W stored [k][n]
__global__ void k_cvt_w(const float* __restrict__ Wl, const float* __restrict__ Wg,
                        unsigned short* __restrict__ Wt) {
  int i = blockIdx.x * blockDim.x + threadIdx.x;
  if (i >= HCOLS * KPAD) return;
  int n = i / KPAD;
  int k = i - n * KPAD;
  float v = 0.f;
  if (k < IN_DIM) {
    v = (n < HIDDEN) ? Wl[(size_t)k * HIDDEN + n] : Wg[(size_t)k * HIDDEN + (n - HIDDEN)];
  }
  Wt[(size_t)n * KPAD + k] = f2bf(v);
}

// ---------------------------------------------------------------- small kernels
__global__ void k_degree(const int* __restrict__ dst, int E, int* __restrict__ deg) {
  int e = blockIdx.x * blockDim.x + threadIdx.x;
  if (e < E) atomicAdd(&deg[dst[e]], 1);
}

__global__ void k_dinv(const int* __restrict__ degL, const int* __restrict__ degG,
                       float* __restrict__ dinvL, float* __restrict__ dinvG) {
  int i = blockIdx.x * blockDim.x + threadIdx.x;
  if (i < N_NODES) {
    dinvL[i] = 1.0f / sqrtf((float)(degL[i] + 1));
    dinvG[i] = 1.0f / sqrtf((float)(degG[i] + 1));
  }
}

__global__ void k_scan_block(const int* __restrict__ cnts, int n,
                             int* __restrict__ incl, int* __restrict__ bsums) {
  __shared__ int s[1024];
  int t = threadIdx.x;
  int i = blockIdx.x * 1024 + t;
  int v = (i < n) ? cnts[i] : 0;
  s[t] = v;
  __syncthreads();
  for (int off = 1; off < 1024; off <<= 1) {
    int x = (t >= off) ? s[t - off] : 0;
    __syncthreads();
    s[t] += x;
    __syncthreads();
  }
  if (i < n) incl[i] = s[t];
  if (t == 1023) bsums[blockIdx.x] = s[1023];
}

__global__ void k_scan_tops(int* __restrict__ bsums, int nb) {
  __shared__ int s[64];
  int t = threadIdx.x;
  if (t < nb) s[t] = bsums[t];
  __syncthreads();
  if (t == 0) {
    int run = 0;
    for (int b = 0; b < nb; b++) { int v = s[b]; s[b] = run; run += v; }
  }
  __syncthreads();
  if (t < nb) bsums[t] = s[t];
}

__global__ void k_scan_fix(const int* __restrict__ incl, const int* __restrict__ boffs,
                           int n, int* __restrict__ row_ptr) {
  int i = blockIdx.x * blockDim.x + threadIdx.x;
  if (i < n) row_ptr[i + 1] = incl[i] + boffs[i >> 10];
  if (i == 0) row_ptr[0] = 0;
}

__global__ void k_scatter(const int* __restrict__ src, const int* __restrict__ dst, int E,
                          const float* __restrict__ dinv, const int* __restrict__ row_ptr,
                          int* __restrict__ cursor, int* __restrict__ s_src,
                          float* __restrict__ s_nrm) {
  int e = blockIdx.x * blockDim.x + threadIdx.x;
  if (e < E) {
    int d = dst[e], s = src[e];
    int pos = row_ptr[d] + atomicAdd(&cursor[d], 1);
    s_src[pos] = s;
    s_nrm[pos] = dinv[s] * dinv[d];
  }
}

__global__ void k_count(const int* __restrict__ batch, int* __restrict__ cnt) {
  int i = blockIdx.x * blockDim.x + threadIdx.x;
  if (i < N_NODES) atomicAdd(&cnt[batch[i]], 1);
}

// ---------------------------------------------------------------- GEMM1 (bf16 MFMA)
// h[MPAD x 512]bf16 = xb[MPAD x KPAD] @ Wt[512 x KPAD]^T
// 128x128 tile, BK=64, 4 waves (2x2), each wave 4x4 16x16x32 fragments.
// LDS: A 128x64 bf16 (16KB) + B 128x64 bf16 (16KB), linear rows of 8x16B chunks,
// XOR swizzle (chunk ^ row&7) applied on the GLOBAL source + on the ds_read.
__launch_bounds__(256)
__global__ void k_mfma_gemm(const unsigned short* __restrict__ Xb,
                            const unsigned short* __restrict__ Wt,
                            unsigned short* __restrict__ H) {
  __shared__ __align__(16) char lds[32768];
  const int tid = threadIdx.x;
  const int lane = tid & 63;
  const int wave = tid >> 6;
  const int wr = wave >> 1, wc = wave & 1;
  const int brow = blockIdx.y * 128;
  const int bcol = blockIdx.x * 128;

  f32x4 acc[4][4];
  const f32x4 zero = {0.f, 0.f, 0.f, 0.f};
#pragma unroll
  for (int m = 0; m < 4; m++)
#pragma unroll
    for (int n = 0; n < 4; n++) acc[m][n] = zero;

  // staging slot geometry (invariant over k-steps)
  int rowA[4], kcS[4], ldsOff[4];
#pragma unroll
  for (int i = 0; i < 4; i++) {
    int s = (i * 4 + wave) * 64 + lane;   // chunk 0..1023
    int row = s >> 3;
    int c = s & 7;
    rowA[i] = row;
    kcS[i] = (c ^ (row & 7)) * 8;         // k element offset of source chunk
    ldsOff[i] = ((i * 4 + wave) * 64) * 16;  // wave-uniform LDS base for this issue
  }

  // fragment read offsets (invariant over k-steps except kk)
  const int fr = lane & 15;       // row/col within 16
  const int fq = lane >> 4;       // k-group 0..3
  const int arow0 = wr * 64 + fr;
  const int brow0 = wc * 64 + fr;
  const int sw = lane & 7;        // == row&7 for both A and B fragment rows

  for (int t = 0; t < KPAD / 64; ++t) {
    const int k0 = t * 64;
    // ---- stage A (4 issues) + B (4 issues), 16B each lane
#pragma unroll
    for (int i = 0; i < 4; i++) {
      const unsigned short* g = Xb + (size_t)(brow + rowA[i]) * KPAD + k0 + kcS[i];
      __builtin_amdgcn_global_load_lds(
          (const __attribute__((address_space(1))) void*)g,
          (__attribute__((address_space(3))) void*)(lds + ldsOff[i]), 16, 0, 0);
    }
#pragma unroll
    for (int i = 0; i < 4; i++) {
      const unsigned short* g = Wt + (size_t)(bcol + rowA[i]) * KPAD + k0 + kcS[i];
      __builtin_amdgcn_global_load_lds(
          (const __attribute__((address_space(1))) void*)g,
          (__attribute__((address_space(3))) void*)(lds + 16384 + ldsOff[i]), 16, 0, 0);
    }
    __syncthreads();  // compiler drains vmcnt before barrier

    // ---- compute 2 x (4x4) MFMAs
#pragma unroll
    for (int kk = 0; kk < 2; kk++) {
      const int cidx = ((kk * 4 + fq) ^ sw) * 16;
      bf16x8 av[4], bv[4];
#pragma unroll
      for (int m = 0; m < 4; m++)
        av[m] = *(const bf16x8*)(lds + (arow0 + m * 16) * 128 + cidx);
#pragma unroll
      for (int n = 0; n < 4; n++)
        bv[n] = *(const bf16x8*)(lds + 16384 + (brow0 + n * 16) * 128 + cidx);
#pragma unroll
      for (int m = 0; m < 4; m++)
#pragma unroll
        for (int n = 0; n < 4; n++)
          acc[m][n] = __builtin_amdgcn_mfma_f32_16x16x32_bf16(av[m], bv[n], acc[m][n], 0, 0, 0);
    }
    __syncthreads();
  }

  // ---- C write (bf16): row = brow + wr*64 + m*16 + fq*4 + j, col = bcol + wc*64 + n*16 + fr
#pragma unroll
  for (int m = 0; m < 4; m++) {
    const int r0 = brow + wr * 64 + m * 16 + fq * 4;
#pragma unroll
    for (int n = 0; n < 4; n++) {
      const int col = bcol + wc * 64 + n * 16 + fr;
#pragma unroll
      for (int j = 0; j < 4; j++) {
        int r = r0 + j;
        if (r < N_NODES) H[(size_t)r * HCOLS + col] = f2bf(acc[m][n][j]);
      }
    }
  }
}

// ------------------------------------------------------- conv1 aggregation (pull)
// one wave per dst node; lane handles 4 consecutive bf16 cols (8B loads)
__global__ void k_agg1(const unsigned short* __restrict__ h, int hoff,
                       const float* __restrict__ dinv, const int* __restrict__ row_ptr,
                       const int* __restrict__ srcs, const float* __restrict__ norms,
                       const float* __restrict__ bias, unsigned short* __restrict__ xl,
                       int xoff) {
  int gt = blockIdx.x * blockDim.x + threadIdx.x;
  int node = gt >> 6;
  int lane = gt & 63;
  if (node >= N_NODES) return;
  float di = dinv[node];
  float w0 = di * di;  // self-loop norm
  ushort4 u = *(const ushort4*)(h + (size_t)node * HCOLS + hoff + lane * 4);
  float a0 = w0 * bf2f(u.x), a1 = w0 * bf2f(u.y), a2 = w0 * bf2f(u.z), a3 = w0 * bf2f(u.w);
  int e0 = row_ptr[node], e1 = row_ptr[node + 1];
  for (int e = e0; e < e1; e++) {
    int s = srcs[e];
    float w = norms[e];
    ushort4 v = *(const ushort4*)(h + (size_t)s * HCOLS + hoff + lane * 4);
    a0 = fmaf(w, bf2f(v.x), a0);
    a1 = fmaf(w, bf2f(v.y), a1);
    a2 = fmaf(w, bf2f(v.z), a2);
    a3 = fmaf(w, bf2f(v.w), a3);
  }
  float4 b = *(const float4*)(bias + lane * 4);
  ushort4 o;
  o.x = f2bf(fmaxf(a0 + b.x, 0.f));
  o.y = f2bf(fmaxf(a1 + b.y, 0.f));
  o.z = f2bf(fmaxf(a2 + b.z, 0.f));
  o.w = f2bf(fmaxf(a3 + b.w, 0.f));
  *(ushort4*)(xl + (size_t)node * HCOLS + xoff + lane * 4) = o;
}

// ---------------------------------------- conv2 fused into pooling: per-graph S
__global__ void k_conv2(const unsigned short* __restrict__ xl, int off,
                        const float* __restrict__ dinv, const int* __restrict__ row_ptr,
                        const int* __restrict__ srcs, const float* __restrict__ norms,
                        const int* __restrict__ batch, float* __restrict__ S) {
  int gt = blockIdx.x * blockDim.x + threadIdx.x;
  int node = gt >> 6;
  int lane = gt & 63;
  if (node >= N_NODES) return;
  float di = dinv[node];
  float w0 = di * di;
  ushort4 u = *(const ushort4*)(xl + (size_t)node * HCOLS + off + lane * 4);
  float a0 = w0 * bf2f(u.x), a1 = w0 * bf2f(u.y), a2 = w0 * bf2f(u.z), a3 = w0 * bf2f(u.w);
  int e0 = row_ptr[node], e1 = row_ptr[node + 1];
  for (int e = e0; e < e1; e++) {
    int s = srcs[e];
    float w = norms[e];
    ushort4 v = *(const ushort4*)(xl + (size_t)s * HCOLS + off + lane * 4);
    a0 = fmaf(w, bf2f(v.x), a0);
    a1 = fmaf(w, bf2f(v.y), a1);
    a2 = fmaf(w, bf2f(v.z), a2);
    a3 = fmaf(w, bf2f(v.w), a3);
  }
  float* sp = S + (size_t)batch[node] * HIDDEN + lane * 4;
  atomicAdd(sp + 0, a0);
  atomicAdd(sp + 1, a1);
  atomicAdd(sp + 2, a2);
  atomicAdd(sp + 3, a3);
}

// ---------------------------------------------------------------- final fuse
__global__ void k_final(const float* __restrict__ S,  // [2][64][256]
                        const float* __restrict__ Wl2, const float* __restrict__ bl2,
                        const float* __restrict__ Wg2, const float* __restrict__ bg2,
                        const float* __restrict__ Wf, const float* __restrict__ bf,
                        const int* __restrict__ cnt, float* __restrict__ out) {
  __shared__ float pl[OUT_DIM], pg[OUT_DIM];
  int g = blockIdx.x, t = threadIdx.x;
  float invc = 1.0f / fmaxf((float)cnt[g], 1.0f);
  const float* Sl = S + (size_t)g * HIDDEN;
  const float* Sg = S + (size_t)N_GRAPHS * HIDDEN + (size_t)g * HIDDEN;
  float al = 0.f, ag = 0.f;
  for (int k = 0; k < HIDDEN; k++) {
    al = fmaf(Sl[k], Wl2[k * OUT_DIM + t], al);
    ag = fmaf(Sg[k], Wg2[k * OUT_DIM + t], ag);
  }
  pl[t] = al * invc + bl2[t];
  pg[t] = ag * invc + bg2[t];
  __syncthreads();
  float o = bf[t];
  for (int j = 0; j < OUT_DIM; j++) {
    o = fmaf(pl[j], Wf[j * OUT_DIM + t], o);
    o = fmaf(pg[j], Wf[(OUT_DIM + j) * OUT_DIM + t], o);
  }
  out[(size_t)g * OUT_DIM + t] = fmaxf(o, 0.f);
}

// ---------------------------------------------------------------- launch
extern "C" void kernel_launch(void* const* d_in, const int* in_sizes, int n_in,
                              void* d_out, int out_size, void* d_ws, size_t ws_size,
                              hipStream_t stream) {
  const float* x = (const float*)d_in[0];
  const int* el = (const int*)d_in[1];
  const int* eg = (const int*)d_in[2];
  const int* batch = (const int*)d_in[3];
  const float* Wl1 = (const float*)d_in[4];
  const float* bl1 = (const float*)d_in[5];
  const float* Wl2 = (const float*)d_in[6];
  const float* bl2 = (const float*)d_in[7];
  const float* Wg1 = (const float*)d_in[8];
  const float* bg1 = (const float*)d_in[9];
  const float* Wg2 = (const float*)d_in[10];
  const float* bg2 = (const float*)d_in[11];
  const float* Wf = (const float*)d_in[12];
  const float* bf = (const float*)d_in[13];
  float* out = (float*)d_out;
  char* ws = (char*)d_ws;

  // ---- workspace layout (256B aligned). Zero-region first (single memset).
  const size_t NPAD = 200192;  // 50000*4 padded
  size_t off = 0;
  int* deg_l = (int*)(ws + off); off += NPAD;
  int* deg_g = (int*)(ws + off); off += NPAD;
  int* cur_l = (int*)(ws + off); off += NPAD;
  int* cur_g = (int*)(ws + off); off += NPAD;
  float* S = (float*)(ws + off); off += (size_t)2 * N_GRAPHS * HIDDEN * 4;  // 128KB
  int* cnt = (int*)(ws + off); off += 256;
  const size_t zero_bytes = off;
  float* dinv_l = (float*)(ws + off); off += NPAD;
  float* dinv_g = (float*)(ws + off); off += NPAD;
  int* row_l = (int*)(ws + off); off += NPAD;
  int* row_g = (int*)(ws + off); off += NPAD;
  int* incl = (int*)(ws + off); off += NPAD;
  int* bsums = (int*)(ws + off); off += 256;
  int* srcs_l = (int*)(ws + off); off += (size_t)EDGES_L * 4;
  float* norm_l = (float*)(ws + off); off += (size_t)EDGES_L * 4;
  int* srcs_g = (int*)(ws + off); off += (size_t)EDGES_G * 4;
  float* norm_g = (float*)(ws + off); off += (size_t)EDGES_G * 4;
  unsigned short* xb = (unsigned short*)(ws + off); off += (size_t)MPAD * KPAD * 2;  // 211 MB
  unsigned short* Wt = (unsigned short*)(ws + off); off += (size_t)HCOLS * KPAD * 2; // 2.2 MB
  unsigned short* h = (unsigned short*)(ws + off); off += (size_t)N_NODES * HCOLS * 2;  // 51.2 MB
  unsigned short* xl = (unsigned short*)(ws + off); off += (size_t)N_NODES * HCOLS * 2; // 51.2 MB
  // total ~340 MB

  const int* srcL = el;
  const int* dstL = el + EDGES_L;
  const int* srcG = eg;
  const int* dstG = eg + EDGES_G;
  float* S_l = S;
  float* S_g = S + (size_t)N_GRAPHS * HIDDEN;

  hipMemsetAsync(ws, 0, zero_bytes, stream);

  // converts (independent of graph preprocessing)
  {
    long long tot = (long long)MPAD * (KPAD / 4);
    k_cvt_x<<<(int)((tot + 255) / 256), 256, 0, stream>>>(x, xb);
    k_cvt_w<<<(HCOLS * KPAD + 255) / 256, 256, 0, stream>>>(Wl1, Wg1, Wt);
  }

  k_degree<<<(EDGES_L + 255) / 256, 256, 0, stream>>>(dstL, EDGES_L, deg_l);
  k_degree<<<(EDGES_G + 255) / 256, 256, 0, stream>>>(dstG, EDGES_G, deg_g);
  k_dinv<<<(N_NODES + 255) / 256, 256, 0, stream>>>(deg_l, deg_g, dinv_l, dinv_g);

  const int NB = (N_NODES + 1023) / 1024;  // 49
  k_scan_block<<<NB, 1024, 0, stream>>>(deg_l, N_NODES, incl, bsums);
  k_scan_tops<<<1, 64, 0, stream>>>(bsums, NB);
  k_scan_fix<<<(N_NODES + 255) / 256, 256, 0, stream>>>(incl, bsums, N_NODES, row_l);
  k_scan_block<<<NB, 1024, 0, stream>>>(deg_g, N_NODES, incl, bsums);
  k_scan_tops<<<1, 64, 0, stream>>>(bsums, NB);
  k_scan_fix<<<(N_NODES + 255) / 256, 256, 0, stream>>>(incl, bsums, N_NODES, row_g);

  k_scatter<<<(EDGES_L + 255) / 256, 256, 0, stream>>>(srcL, dstL, EDGES_L, dinv_l, row_l,
                                                       cur_l, srcs_l, norm_l);
  k_scatter<<<(EDGES_G + 255) / 256, 256, 0, stream>>>(srcG, dstG, EDGES_G, dinv_g, row_g,
                                                       cur_g, srcs_g, norm_g);
  k_count<<<(N_NODES + 255) / 256, 256, 0, stream>>>(batch, cnt);

  // GEMM1: 4 N-tiles x 391 M-tiles
  dim3 ggrid(4, MPAD / 128);
  k_mfma_gemm<<<ggrid, 256, 0, stream>>>(xb, Wt, h);

  const int aggGrid = (N_NODES * 64 + 255) / 256;  // wave-per-node
  k_agg1<<<aggGrid, 256, 0, stream>>>(h, 0, dinv_l, row_l, srcs_l, norm_l, bl1, xl, 0);
  k_agg1<<<aggGrid, 256, 0, stream>>>(h, 256, dinv_g, row_g, srcs_g, norm_g, bg1, xl, 256);

  k_conv2<<<aggGrid, 256, 0, stream>>>(xl, 0, dinv_l, row_l, srcs_l, norm_l, batch, S_l);
  k_conv2<<<aggGrid, 256, 0, stream>>>(xl, 256, dinv_g, row_g, srcs_g, norm_g, batch, S_g);

  k_final<<<N_GRAPHS, OUT_DIM, 0, stream>>>(S, Wl2, bl2, Wg2, bg2, Wf, bf, cnt, out);
}

// Round 3
// 1455.627 us; speedup vs baseline: 2.2606x; 1.4063x over previous
//
#include <hip/hip_runtime.h>
#include <hip/hip_bf16.h>
#include <cstdint>
#include <cstddef>

// GCNEncoder: two-branch GCN on MI355X.
// Round 3: conv2+pool collapsed to S = c^T @ xl  (c[s][g] = sum of edge norms from s
// into graph g, + self-loop). Kills the 12.8M-atomic / random-gather conv2 kernels.
// Pipeline:
//   1) memset zero-region (deg/cursor/cnt/c_l/c_g)
//   2) cvt x -> bf16 xb[50048][2112], W -> bf16 transposed Wt[512][2112]
//   3) degree / dinv / scan -> CSR / scatter / graph counts / c-matrix build
//   4) GEMM1 (MFMA): h[50000x512]bf16 = xb @ Wt^T
//   5) conv1 agg (CSR pull, wave/node, bf16 gather, fp32 acc) + bias + relu -> xl bf16
//   6) k_pool2: Spart[chunk] = c_chunk^T @ xl_chunk  (sequential reads, LDS broadcast)
//      k_pool_reduce: S = sum_chunk Spart
//   7) final: (S@W2)/cnt + b2, concat, @W_fuse + b_fuse, relu -> out[64x128] fp32

#define N_NODES 50000
#define N_GRAPHS 64
#define IN_DIM 2063
#define HIDDEN 256
#define OUT_DIM 128
#define EDGES_L 800000
#define EDGES_G 1600000
#define HCOLS 512   // [local 0..255 | global 256..511]
#define KPAD 2112   // 33 * 64
#define MPAD 50048  // 391 * 128
#define PCH 256                                  // nodes per pool2 chunk
#define NCHUNK ((N_NODES + PCH - 1) / PCH)       // 196

typedef __attribute__((ext_vector_type(8))) __bf16 bf16x8;
typedef __attribute__((ext_vector_type(4))) float f32x4;

__device__ __forceinline__ float bf2f(unsigned short u) {
  union { unsigned int i; float f; } c; c.i = ((unsigned int)u) << 16; return c.f;
}
__device__ __forceinline__ unsigned short f2bf(float f) {
  __hip_bfloat16 h = __float2bfloat16(f);
  return *reinterpret_cast<unsigned short*>(&h);
}

// ---------------------------------------------------------------- converts
__global__ void k_cvt_x(const float* __restrict__ x, unsigned short* __restrict__ xb) {
  const int G = KPAD / 4;  // 528 groups of 4 per row
  long long i = (long long)blockIdx.x * blockDim.x + threadIdx.x;
  if (i >= (long long)MPAD * G) return;
  int row = (int)(i / G);
  int k = (int)(i - (long long)row * G) * 4;
  ushort4 o;
  float v0 = 0.f, v1 = 0.f, v2 = 0.f, v3 = 0.f;
  if (row < N_NODES) {
    const float* xr = x + (size_t)row * IN_DIM;
    if (k + 0 < IN_DIM) v0 = xr[k + 0];
    if (k + 1 < IN_DIM) v1 = xr[k + 1];
    if (k + 2 < IN_DIM) v2 = xr[k + 2];
    if (k + 3 < IN_DIM) v3 = xr[k + 3];
  }
  o.x = f2bf(v0); o.y = f2bf(v1); o.z = f2bf(v2); o.w = f2bf(v3);
  *(ushort4*)(xb + (size_t)row * KPAD + k) = o;
}

__global__ void k_cvt_w(const float* __restrict__ Wl, const float* __restrict__ Wg,
                        unsigned short* __restrict__ Wt) {
  int i = blockIdx.x * blockDim.x + threadIdx.x;
  if (i >= HCOLS * KPAD) return;
  int n = i / KPAD;
  int k = i - n * KPAD;
  float v = 0.f;
  if (k < IN_DIM) {
    v = (n < HIDDEN) ? Wl[(size_t)k * HIDDEN + n] : Wg[(size_t)k * HIDDEN + (n - HIDDEN)];
  }
  Wt[(size_t)n * KPAD + k] = f2bf(v);
}

// ---------------------------------------------------------------- small kernels
__global__ void k_degree(const int* __restrict__ dst, int E, int* __restrict__ deg) {
  int e = blockIdx.x * blockDim.x + threadIdx.x;
  if (e < E) atomicAdd(&deg[dst[e]], 1);
}

__global__ void k_dinv(const int* __restrict__ degL, const int* __restrict__ degG,
                       float* __restrict__ dinvL, float* __restrict__ dinvG) {
  int i = blockIdx.x * blockDim.x + threadIdx.x;
  if (i < N_NODES) {
    dinvL[i] = 1.0f / sqrtf((float)(degL[i] + 1));
    dinvG[i] = 1.0f / sqrtf((float)(degG[i] + 1));
  }
}

__global__ void k_scan_block(const int* __restrict__ cnts, int n,
                             int* __restrict__ incl, int* __restrict__ bsums) {
  __shared__ int s[1024];
  int t = threadIdx.x;
  int i = blockIdx.x * 1024 + t;
  int v = (i < n) ? cnts[i] : 0;
  s[t] = v;
  __syncthreads();
  for (int off = 1; off < 1024; off <<= 1) {
    int x = (t >= off) ? s[t - off] : 0;
    __syncthreads();
    s[t] += x;
    __syncthreads();
  }
  if (i < n) incl[i] = s[t];
  if (t == 1023) bsums[blockIdx.x] = s[1023];
}

__global__ void k_scan_tops(int* __restrict__ bsums, int nb) {
  __shared__ int s[64];
  int t = threadIdx.x;
  if (t < nb) s[t] = bsums[t];
  __syncthreads();
  if (t == 0) {
    int run = 0;
    for (int b = 0; b < nb; b++) { int v = s[b]; s[b] = run; run += v; }
  }
  __syncthreads();
  if (t < nb) bsums[t] = s[t];
}

__global__ void k_scan_fix(const int* __restrict__ incl, const int* __restrict__ boffs,
                           int n, int* __restrict__ row_ptr) {
  int i = blockIdx.x * blockDim.x + threadIdx.x;
  if (i < n) row_ptr[i + 1] = incl[i] + boffs[i >> 10];
  if (i == 0) row_ptr[0] = 0;
}

__global__ void k_scatter(const int* __restrict__ src, const int* __restrict__ dst, int E,
                          const float* __restrict__ dinv, const int* __restrict__ row_ptr,
                          int* __restrict__ cursor, int* __restrict__ s_src,
                          float* __restrict__ s_nrm) {
  int e = blockIdx.x * blockDim.x + threadIdx.x;
  if (e < E) {
    int d = dst[e], s = src[e];
    int pos = row_ptr[d] + atomicAdd(&cursor[d], 1);
    s_src[pos] = s;
    s_nrm[pos] = dinv[s] * dinv[d];
  }
}

__global__ void k_count(const int* __restrict__ batch, int* __restrict__ cnt) {
  int i = blockIdx.x * blockDim.x + threadIdx.x;
  if (i < N_NODES) atomicAdd(&cnt[batch[i]], 1);
}

// c[s][g] += norm_e for each edge s->dst in graph g  (low-contention scatter)
__global__ void k_cbuild(const int* __restrict__ src, const int* __restrict__ dst, int E,
                         const float* __restrict__ dinv, const int* __restrict__ batch,
                         float* __restrict__ c) {
  int e = blockIdx.x * blockDim.x + threadIdx.x;
  if (e < E) {
    int s = src[e], d = dst[e];
    atomicAdd(&c[(size_t)s * 64 + batch[d]], dinv[s] * dinv[d]);
  }
}

__global__ void k_cself(const int* __restrict__ batch, const float* __restrict__ dinvL,
                        const float* __restrict__ dinvG, float* __restrict__ cL,
                        float* __restrict__ cG) {
  int i = blockIdx.x * blockDim.x + threadIdx.x;
  if (i < N_NODES) {
    int g = batch[i];
    atomicAdd(&cL[(size_t)i * 64 + g], dinvL[i] * dinvL[i]);
    atomicAdd(&cG[(size_t)i * 64 + g], dinvG[i] * dinvG[i]);
  }
}

// ---------------------------------------------------------------- GEMM1 (bf16 MFMA)
__launch_bounds__(256)
__global__ void k_mfma_gemm(const unsigned short* __restrict__ Xb,
                            const unsigned short* __restrict__ Wt,
                            unsigned short* __restrict__ H) {
  __shared__ __align__(16) char lds[32768];
  const int tid = threadIdx.x;
  const int lane = tid & 63;
  const int wave = tid >> 6;
  const int wr = wave >> 1, wc = wave & 1;
  const int brow = blockIdx.y * 128;
  const int bcol = blockIdx.x * 128;

  f32x4 acc[4][4];
  const f32x4 zero = {0.f, 0.f, 0.f, 0.f};
#pragma unroll
  for (int m = 0; m < 4; m++)
#pragma unroll
    for (int n = 0; n < 4; n++) acc[m][n] = zero;

  int rowA[4], kcS[4], ldsOff[4];
#pragma unroll
  for (int i = 0; i < 4; i++) {
    int s = (i * 4 + wave) * 64 + lane;
    int row = s >> 3;
    int c = s & 7;
    rowA[i] = row;
    kcS[i] = (c ^ (row & 7)) * 8;
    ldsOff[i] = ((i * 4 + wave) * 64) * 16;
  }

  const int fr = lane & 15;
  const int fq = lane >> 4;
  const int arow0 = wr * 64 + fr;
  const int brow0 = wc * 64 + fr;
  const int sw = lane & 7;

  for (int t = 0; t < KPAD / 64; ++t) {
    const int k0 = t * 64;
#pragma unroll
    for (int i = 0; i < 4; i++) {
      const unsigned short* g = Xb + (size_t)(brow + rowA[i]) * KPAD + k0 + kcS[i];
      __builtin_amdgcn_global_load_lds(
          (const __attribute__((address_space(1))) void*)g,
          (__attribute__((address_space(3))) void*)(lds + ldsOff[i]), 16, 0, 0);
    }
#pragma unroll
    for (int i = 0; i < 4; i++) {
      const unsigned short* g = Wt + (size_t)(bcol + rowA[i]) * KPAD + k0 + kcS[i];
      __builtin_amdgcn_global_load_lds(
          (const __attribute__((address_space(1))) void*)g,
          (__attribute__((address_space(3))) void*)(lds + 16384 + ldsOff[i]), 16, 0, 0);
    }
    __syncthreads();

#pragma unroll
    for (int kk = 0; kk < 2; kk++) {
      const int cidx = ((kk * 4 + fq) ^ sw) * 16;
      bf16x8 av[4], bv[4];
#pragma unroll
      for (int m = 0; m < 4; m++)
        av[m] = *(const bf16x8*)(lds + (arow0 + m * 16) * 128 + cidx);
#pragma unroll
      for (int n = 0; n < 4; n++)
        bv[n] = *(const bf16x8*)(lds + 16384 + (brow0 + n * 16) * 128 + cidx);
#pragma unroll
      for (int m = 0; m < 4; m++)
#pragma unroll
        for (int n = 0; n < 4; n++)
          acc[m][n] = __builtin_amdgcn_mfma_f32_16x16x32_bf16(av[m], bv[n], acc[m][n], 0, 0, 0);
    }
    __syncthreads();
  }

#pragma unroll
  for (int m = 0; m < 4; m++) {
    const int r0 = brow + wr * 64 + m * 16 + fq * 4;
#pragma unroll
    for (int n = 0; n < 4; n++) {
      const int col = bcol + wc * 64 + n * 16 + fr;
#pragma unroll
      for (int j = 0; j < 4; j++) {
        int r = r0 + j;
        if (r < N_NODES) H[(size_t)r * HCOLS + col] = f2bf(acc[m][n][j]);
      }
    }
  }
}

// ------------------------------------------------------- conv1 aggregation (pull)
__global__ void k_agg1(const unsigned short* __restrict__ h, int hoff,
                       const float* __restrict__ dinv, const int* __restrict__ row_ptr,
                       const int* __restrict__ srcs, const float* __restrict__ norms,
                       const float* __restrict__ bias, unsigned short* __restrict__ xl,
                       int xoff) {
  int gt = blockIdx.x * blockDim.x + threadIdx.x;
  int node = gt >> 6;
  int lane = gt & 63;
  if (node >= N_NODES) return;
  float di = dinv[node];
  float w0 = di * di;
  ushort4 u = *(const ushort4*)(h + (size_t)node * HCOLS + hoff + lane * 4);
  float a0 = w0 * bf2f(u.x), a1 = w0 * bf2f(u.y), a2 = w0 * bf2f(u.z), a3 = w0 * bf2f(u.w);
  int e0 = row_ptr[node], e1 = row_ptr[node + 1];
  for (int e = e0; e < e1; e++) {
    int s = srcs[e];
    float w = norms[e];
    ushort4 v = *(const ushort4*)(h + (size_t)s * HCOLS + hoff + lane * 4);
    a0 = fmaf(w, bf2f(v.x), a0);
    a1 = fmaf(w, bf2f(v.y), a1);
    a2 = fmaf(w, bf2f(v.z), a2);
    a3 = fmaf(w, bf2f(v.w), a3);
  }
  float4 b = *(const float4*)(bias + lane * 4);
  ushort4 o;
  o.x = f2bf(fmaxf(a0 + b.x, 0.f));
  o.y = f2bf(fmaxf(a1 + b.y, 0.f));
  o.z = f2bf(fmaxf(a2 + b.z, 0.f));
  o.w = f2bf(fmaxf(a3 + b.w, 0.f));
  *(ushort4*)(xl + (size_t)node * HCOLS + xoff + lane * 4) = o;
}

// --------------------------------- pool2: Spart[br][chunk][g][col] = c^T @ xl chunk
__launch_bounds__(256)
__global__ void k_pool2(const unsigned short* __restrict__ xl,
                        const float* __restrict__ cL, const float* __restrict__ cG,
                        float* __restrict__ Spart) {
  __shared__ float cs[64][64];  // 16 KB: 64 nodes x 64 graphs
  const int t = threadIdx.x;    // col 0..255
  const int chunk = blockIdx.x;
  const int br = blockIdx.y;
  const float* __restrict__ C = br ? cG : cL;
  const int xoff = br ? 256 : 0;
  const int n0 = chunk * PCH;
  float acc[64];
#pragma unroll
  for (int g = 0; g < 64; g++) acc[g] = 0.f;

  for (int tile = 0; tile < PCH; tile += 64) {
    const int base = n0 + tile;
    __syncthreads();
#pragma unroll
    for (int i = 0; i < 16; i++) {
      int idx = i * 256 + t;  // 0..4095
      int nn = idx >> 6, gg = idx & 63;
      int node = base + nn;
      cs[nn][gg] = (node < N_NODES) ? C[(size_t)node * 64 + gg] : 0.f;
    }
    __syncthreads();
    for (int nn = 0; nn < 64; nn++) {
      int node = base + nn;
      float v = (node < N_NODES) ? bf2f(xl[(size_t)node * HCOLS + xoff + t]) : 0.f;
#pragma unroll
      for (int g4 = 0; g4 < 16; g4++) {
        float4 cv = *(const float4*)&cs[nn][g4 * 4];
        acc[g4 * 4 + 0] = fmaf(cv.x, v, acc[g4 * 4 + 0]);
        acc[g4 * 4 + 1] = fmaf(cv.y, v, acc[g4 * 4 + 1]);
        acc[g4 * 4 + 2] = fmaf(cv.z, v, acc[g4 * 4 + 2]);
        acc[g4 * 4 + 3] = fmaf(cv.w, v, acc[g4 * 4 + 3]);
      }
    }
  }
  float* sp = Spart + ((size_t)br * NCHUNK + chunk) * 16384 + t;
#pragma unroll
  for (int g = 0; g < 64; g++) sp[g * 256] = acc[g];
}

__global__ void k_pool_reduce(const float* __restrict__ Spart, float* __restrict__ S) {
  int i = blockIdx.x * blockDim.x + threadIdx.x;  // 0..32767
  if (i >= 2 * 16384) return;
  int br = i >> 14, idx = i & 16383;
  const float* p = Spart + (size_t)br * NCHUNK * 16384 + idx;
  float s = 0.f;
  for (int ch = 0; ch < NCHUNK; ch++) s += p[(size_t)ch * 16384];
  S[i] = s;
}

// ---------------------------------------------------------------- final fuse
__global__ void k_final(const float* __restrict__ S,  // [2][64][256]
                        const float* __restrict__ Wl2, const float* __restrict__ bl2,
                        const float* __restrict__ Wg2, const float* __restrict__ bg2,
                        const float* __restrict__ Wf, const float* __restrict__ bf,
                        const int* __restrict__ cnt, float* __restrict__ out) {
  __shared__ float pl[OUT_DIM], pg[OUT_DIM];
  int g = blockIdx.x, t = threadIdx.x;
  float invc = 1.0f / fmaxf((float)cnt[g], 1.0f);
  const float* Sl = S + (size_t)g * HIDDEN;
  const float* Sg = S + (size_t)N_GRAPHS * HIDDEN + (size_t)g * HIDDEN;
  float al = 0.f, ag = 0.f;
  for (int k = 0; k < HIDDEN; k++) {
    al = fmaf(Sl[k], Wl2[k * OUT_DIM + t], al);
    ag = fmaf(Sg[k], Wg2[k * OUT_DIM + t], ag);
  }
  pl[t] = al * invc + bl2[t];
  pg[t] = ag * invc + bg2[t];
  __syncthreads();
  float o = bf[t];
  for (int j = 0; j < OUT_DIM; j++) {
    o = fmaf(pl[j], Wf[j * OUT_DIM + t], o);
    o = fmaf(pg[j], Wf[(OUT_DIM + j) * OUT_DIM + t], o);
  }
  out[(size_t)g * OUT_DIM + t] = fmaxf(o, 0.f);
}

// ---------------------------------------------------------------- launch
extern "C" void kernel_launch(void* const* d_in, const int* in_sizes, int n_in,
                              void* d_out, int out_size, void* d_ws, size_t ws_size,
                              hipStream_t stream) {
  const float* x = (const float*)d_in[0];
  const int* el = (const int*)d_in[1];
  const int* eg = (const int*)d_in[2];
  const int* batch = (const int*)d_in[3];
  const float* Wl1 = (const float*)d_in[4];
  const float* bl1 = (const float*)d_in[5];
  const float* Wl2 = (const float*)d_in[6];
  const float* bl2 = (const float*)d_in[7];
  const float* Wg1 = (const float*)d_in[8];
  const float* bg1 = (const float*)d_in[9];
  const float* Wg2 = (const float*)d_in[10];
  const float* bg2 = (const float*)d_in[11];
  const float* Wf = (const float*)d_in[12];
  const float* bf = (const float*)d_in[13];
  float* out = (float*)d_out;
  char* ws = (char*)d_ws;

  // ---- workspace layout (256B aligned). Zero-region first (single memset).
  const size_t NPAD = 200192;  // 50000*4 padded
  size_t off = 0;
  int* deg_l = (int*)(ws + off); off += NPAD;
  int* deg_g = (int*)(ws + off); off += NPAD;
  int* cur_l = (int*)(ws + off); off += NPAD;
  int* cur_g = (int*)(ws + off); off += NPAD;
  int* cnt = (int*)(ws + off); off += 256;
  float* c_l = (float*)(ws + off); off += (size_t)N_NODES * 64 * 4;  // 12.8 MB
  float* c_g = (float*)(ws + off); off += (size_t)N_NODES * 64 * 4;  // 12.8 MB
  const size_t zero_bytes = off;
  float* S = (float*)(ws + off); off += (size_t)2 * N_GRAPHS * HIDDEN * 4;
  float* dinv_l = (float*)(ws + off); off += NPAD;
  float* dinv_g = (float*)(ws + off); off += NPAD;
  int* row_l = (int*)(ws + off); off += NPAD;
  int* row_g = (int*)(ws + off); off += NPAD;
  int* incl = (int*)(ws + off); off += NPAD;
  int* bsums = (int*)(ws + off); off += 256;
  int* srcs_l = (int*)(ws + off); off += (size_t)EDGES_L * 4;
  float* norm_l = (float*)(ws + off); off += (size_t)EDGES_L * 4;
  int* srcs_g = (int*)(ws + off); off += (size_t)EDGES_G * 4;
  float* norm_g = (float*)(ws + off); off += (size_t)EDGES_G * 4;
  unsigned short* xb = (unsigned short*)(ws + off); off += (size_t)MPAD * KPAD * 2;  // 211 MB
  unsigned short* Wt = (unsigned short*)(ws + off); off += (size_t)HCOLS * KPAD * 2;
  unsigned short* h = (unsigned short*)(ws + off); off += (size_t)N_NODES * HCOLS * 2;
  unsigned short* xl = (unsigned short*)(ws + off); off += (size_t)N_NODES * HCOLS * 2;
  // Spart aliases xb: xb is dead after k_mfma_gemm, Spart written after (pool2).
  float* Spart = (float*)xb;  // 2*196*16384*4 = 25.7 MB << 211 MB

  const int* srcL = el;
  const int* dstL = el + EDGES_L;
  const int* srcG = eg;
  const int* dstG = eg + EDGES_G;

  hipMemsetAsync(ws, 0, zero_bytes, stream);

  {
    long long tot = (long long)MPAD * (KPAD / 4);
    k_cvt_x<<<(int)((tot + 255) / 256), 256, 0, stream>>>(x, xb);
    k_cvt_w<<<(HCOLS * KPAD + 255) / 256, 256, 0, stream>>>(Wl1, Wg1, Wt);
  }

  k_degree<<<(EDGES_L + 255) / 256, 256, 0, stream>>>(dstL, EDGES_L, deg_l);
  k_degree<<<(EDGES_G + 255) / 256, 256, 0, stream>>>(dstG, EDGES_G, deg_g);
  k_dinv<<<(N_NODES + 255) / 256, 256, 0, stream>>>(deg_l, deg_g, dinv_l, dinv_g);

  const int NB = (N_NODES + 1023) / 1024;  // 49
  k_scan_block<<<NB, 1024, 0, stream>>>(deg_l, N_NODES, incl, bsums);
  k_scan_tops<<<1, 64, 0, stream>>>(bsums, NB);
  k_scan_fix<<<(N_NODES + 255) / 256, 256, 0, stream>>>(incl, bsums, N_NODES, row_l);
  k_scan_block<<<NB, 1024, 0, stream>>>(deg_g, N_NODES, incl, bsums);
  k_scan_tops<<<1, 64, 0, stream>>>(bsums, NB);
  k_scan_fix<<<(N_NODES + 255) / 256, 256, 0, stream>>>(incl, bsums, N_NODES, row_g);

  k_scatter<<<(EDGES_L + 255) / 256, 256, 0, stream>>>(srcL, dstL, EDGES_L, dinv_l, row_l,
                                                       cur_l, srcs_l, norm_l);
  k_scatter<<<(EDGES_G + 255) / 256, 256, 0, stream>>>(srcG, dstG, EDGES_G, dinv_g, row_g,
                                                       cur_g, srcs_g, norm_g);
  k_count<<<(N_NODES + 255) / 256, 256, 0, stream>>>(batch, cnt);

  // c-matrix build (needs dinv only)
  k_cbuild<<<(EDGES_L + 255) / 256, 256, 0, stream>>>(srcL, dstL, EDGES_L, dinv_l, batch, c_l);
  k_cbuild<<<(EDGES_G + 255) / 256, 256, 0, stream>>>(srcG, dstG, EDGES_G, dinv_g, batch, c_g);
  k_cself<<<(N_NODES + 255) / 256, 256, 0, stream>>>(batch, dinv_l, dinv_g, c_l, c_g);

  // GEMM1: 4 N-tiles x 391 M-tiles
  dim3 ggrid(4, MPAD / 128);
  k_mfma_gemm<<<ggrid, 256, 0, stream>>>(xb, Wt, h);

  const int aggGrid = (N_NODES * 64 + 255) / 256;  // wave-per-node
  k_agg1<<<aggGrid, 256, 0, stream>>>(h, 0, dinv_l, row_l, srcs_l, norm_l, bl1, xl, 0);
  k_agg1<<<aggGrid, 256, 0, stream>>>(h, 256, dinv_g, row_g, srcs_g, norm_g, bg1, xl, 256);

  // pool2 (reads xl + c sequentially; writes partials; aliased over dead xb)
  dim3 pgrid(NCHUNK, 2);
  k_pool2<<<pgrid, 256, 0, stream>>>(xl, c_l, c_g, Spart);
  k_pool_reduce<<<(2 * 16384 + 255) / 256, 256, 0, stream>>>(Spart, S);

  k_final<<<N_GRAPHS, OUT_DIM, 0, stream>>>(S, Wl2, bl2, Wg2, bg2, Wf, bf, cnt, out);
}